// Round 4
// baseline (673.230 us; speedup 1.0000x reference)
//
#include <hip/hip_runtime.h>

typedef unsigned short ushort_t;
typedef __attribute__((ext_vector_type(8))) __bf16 bf16x8;
typedef __attribute__((ext_vector_type(8))) ushort_t u16x8;
typedef __attribute__((ext_vector_type(4))) float f32x4;
typedef __attribute__((ext_vector_type(4))) unsigned int u32x4;

__device__ __forceinline__ ushort_t f2bf(float f) {
  union { float f; unsigned int u; } v; v.f = f;
  unsigned int u = v.u;
  u += 0x7fffu + ((u >> 16) & 1u);   // round-to-nearest-even
  return (ushort_t)(u >> 16);
}

__device__ __forceinline__ unsigned cvt_pk_bf16(float lo, float hi) {
  unsigned r;
  asm("v_cvt_pk_bf16_f32 %0, %1, %2" : "=v"(r) : "v"(lo), "v"(hi));
  return r;
}

// ---------------- kernel 1: row softmax of energy + u[b][i] = sum_j A[i][j]*b_v[j]
__global__ __launch_bounds__(64) void softmax_k(
    const float* __restrict__ energy, const float* __restrict__ bval,
    float* __restrict__ Asm, float* __restrict__ u)
{
  const int row = blockIdx.x;             // b*256 + i
  const int l = threadIdx.x;              // 0..63
  const float* e = energy + (size_t)row * 256;
  float v0 = e[l], v1 = e[l + 64], v2 = e[l + 128], v3 = e[l + 192];
  float mx = fmaxf(fmaxf(v0, v1), fmaxf(v2, v3));
  #pragma unroll
  for (int o = 32; o > 0; o >>= 1) mx = fmaxf(mx, __shfl_xor(mx, o));
  v0 = __expf(v0 - mx); v1 = __expf(v1 - mx);
  v2 = __expf(v2 - mx); v3 = __expf(v3 - mx);
  float s = v0 + v1 + v2 + v3;
  #pragma unroll
  for (int o = 32; o > 0; o >>= 1) s += __shfl_xor(s, o);
  const float inv = 1.0f / s;
  v0 *= inv; v1 *= inv; v2 *= inv; v3 *= inv;
  float* Ao = Asm + (size_t)row * 256;
  Ao[l] = v0; Ao[l + 64] = v1; Ao[l + 128] = v2; Ao[l + 192] = v3;
  float ub = v0 * bval[l] + v1 * bval[l + 64] + v2 * bval[l + 128] + v3 * bval[l + 192];
  #pragma unroll
  for (int o = 32; o > 0; o >>= 1) ub += __shfl_xor(ub, o);
  if (l == 0) u[row] = ub;
}

// ---------------- kernel 2: batched fp32 GEMM C = A @ B, 64x64 tile, k-major LDS
__global__ __launch_bounds__(256) void gemm2_k(
    const float* __restrict__ A, int lda, int sA,
    const float* __restrict__ B, int ldb, int sB,
    float* __restrict__ C, int ldc, int sC, int K)
{
  const int bz = blockIdx.z;
  A += (size_t)bz * sA; B += (size_t)bz * sB; C += (size_t)bz * sC;
  const int m0 = blockIdx.y * 64, n0 = blockIdx.x * 64;
  __shared__ float AsT[16][68];   // [k][m], 272B rows (16B-aligned)
  __shared__ float Bs[16][68];    // [k][n]
  const int t = threadIdx.x, tx = t & 15, ty = t >> 4;
  const int ar = t >> 2, ak = (t & 3) * 4;     // A stage: row, k-quad
  const int br = t >> 4, bc = (t & 15) * 4;    // B stage: k-row, col-quad
  float acc[4][4] = {};
  for (int k0 = 0; k0 < K; k0 += 16) {
    // issue loads before the sync so they overlap previous iteration's FMAs
    float4 av = *(const float4*)(A + (size_t)(m0 + ar) * lda + k0 + ak);
    float4 bv = *(const float4*)(B + (size_t)(k0 + br) * ldb + n0 + bc);
    __syncthreads();
    AsT[ak][ar] = av.x; AsT[ak + 1][ar] = av.y;
    AsT[ak + 2][ar] = av.z; AsT[ak + 3][ar] = av.w;
    *(float4*)&Bs[br][bc] = bv;
    __syncthreads();
    #pragma unroll
    for (int kk = 0; kk < 16; ++kk) {
      float4 a4 = *(const float4*)&AsT[kk][ty * 4];
      float4 b4 = *(const float4*)&Bs[kk][tx * 4];
      const float aa[4] = {a4.x, a4.y, a4.z, a4.w};
      const float bb[4] = {b4.x, b4.y, b4.z, b4.w};
      #pragma unroll
      for (int i = 0; i < 4; ++i)
        #pragma unroll
        for (int j = 0; j < 4; ++j) acc[i][j] = fmaf(aa[i], bb[j], acc[i][j]);
    }
  }
  #pragma unroll
  for (int i = 0; i < 4; ++i) {
    float4 cv = {acc[i][0], acc[i][1], acc[i][2], acc[i][3]};
    *(float4*)(C + (size_t)(m0 + ty * 4 + i) * ldc + n0 + tx * 4) = cv;
  }
}

// ---------------- kernel 3: c[b][o] = gamma*(W_re[o,:]·u[b,:] + b_re[o])
__global__ __launch_bounds__(256) void bias_k(
    const float* __restrict__ wre, const float* __restrict__ u,
    const float* __restrict__ bre, const float* __restrict__ gp,
    float* __restrict__ c)
{
  const int idx = blockIdx.x * 256 + threadIdx.x;  // 0..4095
  const int b = idx >> 9, o = idx & 511;
  const float* wrow = wre + (size_t)o * 256;
  const float* uu = u + b * 256;
  float s = 0.f;
  for (int j = 0; j < 256; ++j) s += wrow[j] * uu[j];
  c[idx] = gp[0] * (s + bre[o]);
}

// ---------------- kernel 4: P (fp32 row-major) -> gamma-scaled bf16 fragment-linear
// Ps flat index = (((b*16 + kt)*32 + mt)*64 + lane)*8 + j
//   lane = kg*16 + (m&15), kg = (k>>3)&3, kt = k>>5, mt = m>>4, j = k&7
__global__ __launch_bounds__(256) void pswz_k(
    const float* __restrict__ P, const float* __restrict__ gp,
    ushort_t* __restrict__ Ps)
{
  const int d = blockIdx.x * 256 + threadIdx.x;    // 0..2097151
  const int j = d & 7, lane = (d >> 3) & 63, mt = (d >> 9) & 31;
  const int kt = (d >> 14) & 15, b = d >> 18;
  const int kg = lane >> 4, mr = lane & 15;
  const int m = mt * 16 + mr, k = kt * 32 + kg * 8 + j;
  Ps[d] = f2bf(gp[0] * P[((size_t)b * 512 + m) * 512 + k]);
}

// ---------------- kernel 5: out[b] = (gamma*P[b])@x[b] + 2*x[b] + c[b]
// 128x128 tile, BK=64, 4 waves (2x2). Software-pipelined:
//   iter kt: {ds_write tile kt+1 (x loaded in iter kt-1)} | {issue x(kt+2)} |
//            {ds_read B + 32 MFMA with af(kt) in regs} | {issue af(kt+2) (L2)}
// sched_barrier(0) fences pin the load-issue phases so the compiler cannot
// sink the prefetch to its use (round-3 profile: VGPR=84 proved it had).
__global__ __launch_bounds__(256) void main_k(
    const ushort_t* __restrict__ Ps, const float* __restrict__ x,
    const float* __restrict__ cvec, float* __restrict__ out)
{
  __shared__ __align__(16) ushort_t Blds[2][8192];  // [buf][col*64 + k], XOR-swizzled

  const int bid = blockIdx.x;
  const int b = bid & 7;             // batch -> XCD pin (nwg%8==0, bijective)
  const int yb = (bid >> 3) & 3;
  const int n0 = (bid >> 5) * 128;
  const int m0 = yb * 128;

  const int t = threadIdx.x, lane = t & 63;
  const int w = t >> 6, wr = w >> 1, wc = w & 1;

  const float* xb = x + (size_t)b * (512 * 16384);
  const int c4 = t & 31;           // cols 4c4..4c4+3
  const int r0 = (t >> 5) * 8;     // k rows r0..r0+7 within the 64-row tile
  const int xcol = n0 + 4 * c4;
  const int mtb = yb * 8 + wr * 4;

  f32x4 acc[4][4];
  #pragma unroll
  for (int i = 0; i < 4; ++i)
    #pragma unroll
    for (int j = 0; j < 4; ++j) acc[i][j] = (f32x4){0.f, 0.f, 0.f, 0.f};

  float4 stg[8];
  bf16x8 afA[8], afB[8];   // [kk*4+i] register double-buffer for A fragments

  auto loadTile = [&](int kt) {
    #pragma unroll
    for (int i = 0; i < 8; ++i)
      stg[i] = *(const float4*)(xb + (size_t)(kt * 64 + r0 + i) * 16384 + xcol);
  };
  auto loadA = [&](int kt, bf16x8* dst) {
    #pragma unroll
    for (int kk = 0; kk < 2; ++kk)
      #pragma unroll
      for (int i = 0; i < 4; ++i)
        dst[kk * 4 + i] = *(const bf16x8*)(
            Ps + ((size_t)((b * 16 + (kt * 2 + kk)) * 32 + (mtb + i))) * 512
               + (size_t)lane * 8);
  };
  auto writeTile = [&](int bufI) {
    char* base = (char*)&Blds[bufI][0];
    #pragma unroll
    for (int cc = 0; cc < 4; ++cc) {
      const int col = 4 * c4 + cc;
      u32x4 wv;
      #pragma unroll
      for (int p = 0; p < 4; ++p) {
        const float* f0 = (const float*)&stg[2 * p];
        const float* f1 = (const float*)&stg[2 * p + 1];
        wv[p] = cvt_pk_bf16(f0[cc], f1[cc]);   // lo=row 2p, hi=row 2p+1
      }
      const int swz = ((col >> 2) ^ col) & 7;
      const int off = col * 128 + ((r0 * 2) ^ (swz << 4));
      *(u32x4*)(base + off) = wv;
    }
  };

  // prologue: af(0), af(1) issued first; tile 0 staged synchronously; x(1) in flight
  loadA(0, afA);
  loadA(1, afB);
  loadTile(0);
  writeTile(0);
  loadTile(1);
  __syncthreads();

  #pragma unroll
  for (int kt = 0; kt < 8; ++kt) {
    bf16x8* cur = (kt & 1) ? afB : afA;

    // phase C-early: stage tile kt+1 (stg holds x(kt+1), loaded one iter ago)
    if (kt < 7) writeTile((kt + 1) & 1);
    __builtin_amdgcn_sched_barrier(0);

    // phase A: issue x(kt+2) HBM loads
    if (kt < 6) loadTile(kt + 2);
    __builtin_amdgcn_sched_barrier(0);

    // phase B: ds_read B fragments + MFMA with af(kt) already in registers
    const char* base = (const char*)&Blds[kt & 1][0];
    #pragma unroll
    for (int kk = 0; kk < 2; ++kk) {
      #pragma unroll
      for (int j = 0; j < 4; ++j) {
        const int col = wc * 64 + j * 16 + (lane & 15);
        const int kb = kk * 64 + (lane >> 4) * 16;
        const int swz = ((col >> 2) ^ col) & 7;
        const bf16x8 bf = *(const bf16x8*)(base + col * 128 + (kb ^ (swz << 4)));
        #pragma unroll
        for (int i = 0; i < 4; ++i)
          acc[i][j] = __builtin_amdgcn_mfma_f32_16x16x32_bf16(cur[kk * 4 + i], bf, acc[i][j], 0, 0, 0);
      }
    }

    // issue af(kt+2) (L2-resident Ps) into the buffer MFMA just released
    if (kt < 6) loadA(kt + 2, cur);
    __syncthreads();
  }

  // epilogue: out = acc + 2*x + c   (C/D layout: col=lane&15, row=(lane>>4)*4+r)
  float* ob = out + (size_t)b * (512 * 16384);
  const float* cb_base = cvec + b * 512 + m0;
  #pragma unroll
  for (int i = 0; i < 4; ++i) {
    #pragma unroll
    for (int r = 0; r < 4; ++r) {
      const int lm = wr * 64 + i * 16 + (lane >> 4) * 4 + r;
      const size_t gm = (size_t)(m0 + lm);
      const float cb = cb_base[lm];
      #pragma unroll
      for (int j = 0; j < 4; ++j) {
        const int gn = n0 + wc * 64 + j * 16 + (lane & 15);
        const size_t off = gm * 16384 + gn;
        ob[off] = fmaf(2.0f, xb[off], acc[i][j][r] + cb);
      }
    }
  }
}

extern "C" void kernel_launch(void* const* d_in, const int* in_sizes, int n_in,
                              void* d_out, int out_size, void* d_ws, size_t ws_size,
                              hipStream_t stream) {
  const float* energy  = (const float*)d_in[0];  // [8,256,256]
  const float* x       = (const float*)d_in[1];  // [8,512,128,128]
  const float* w_value = (const float*)d_in[2];  // [256,512]
  const float* b_value = (const float*)d_in[3];  // [256]
  const float* w_re    = (const float*)d_in[4];  // [512,256]
  const float* b_re    = (const float*)d_in[5];  // [512]
  const float* gamma   = (const float*)d_in[6];  // [1]
  float* out = (float*)d_out;

  char* ws = (char*)d_ws;
  float*    Asm = (float*)(ws);                  // 8*256*256 f32   (2 MB)
  float*    u   = (float*)(ws + 2097152);        // 8*256 f32       (8 KB)
  float*    T   = (float*)(ws + 2105344);        // 8*512*256 f32   (4 MB)
  float*    P   = (float*)(ws + 6299648);        // 8*512*512 f32   (8 MB)
  float*    c   = (float*)(ws + 14688256);       // 8*512 f32       (16 KB)
  ushort_t* Ps  = (ushort_t*)(ws + 14704640);    // 8*512*512 bf16  (4 MB)

  // A = softmax(energy), u = A @ b_value
  softmax_k<<<2048, 64, 0, stream>>>(energy, b_value, Asm, u);
  // T[b] = W_re @ A[b]          (512x256, K=256)
  gemm2_k<<<dim3(4, 8, 8), 256, 0, stream>>>(w_re, 256, 0,
                                             Asm, 256, 256 * 256,
                                             T, 256, 512 * 256, 256);
  // P[b] = T[b] @ W_v           (512x512, K=256)
  gemm2_k<<<dim3(8, 8, 8), 256, 0, stream>>>(T, 256, 512 * 256,
                                             w_value, 512, 0,
                                             P, 512, 512 * 512, 256);
  // c[b] = gamma*(W_re @ u[b] + b_re)
  bias_k<<<16, 256, 0, stream>>>(w_re, u, b_re, gamma, c);
  // P -> gamma-scaled bf16 fragment-linear
  pswz_k<<<8192, 256, 0, stream>>>(P, gamma, Ps);
  // out[b] = (gamma*P[b]) @ x[b] + 2*x[b] + c[b]
  main_k<<<4096, 256, 0, stream>>>(Ps, x, c, out);
}

// Round 5
// 663.066 us; speedup vs baseline: 1.0153x; 1.0153x over previous
//
#include <hip/hip_runtime.h>

typedef unsigned short ushort_t;
typedef __attribute__((ext_vector_type(8))) __bf16 bf16x8;
typedef __attribute__((ext_vector_type(8))) ushort_t u16x8;
typedef __attribute__((ext_vector_type(4))) float f32x4;
typedef __attribute__((ext_vector_type(4))) unsigned int u32x4;

__device__ __forceinline__ ushort_t f2bf(float f) {
  union { float f; unsigned int u; } v; v.f = f;
  unsigned int u = v.u;
  u += 0x7fffu + ((u >> 16) & 1u);   // round-to-nearest-even
  return (ushort_t)(u >> 16);
}

__device__ __forceinline__ unsigned cvt_pk_bf16(float lo, float hi) {
  unsigned r;
  asm("v_cvt_pk_bf16_f32 %0, %1, %2" : "=v"(r) : "v"(lo), "v"(hi));
  return r;
}

// LDS-visibility-only barrier: do NOT drain vmcnt (prefetches stay in flight).
__device__ __forceinline__ void lds_barrier() {
  asm volatile("s_waitcnt lgkmcnt(0)" ::: "memory");
  __builtin_amdgcn_s_barrier();
}

// ---------------- kernel 1: row softmax of energy + u[b][i] = sum_j A[i][j]*b_v[j]
__global__ __launch_bounds__(64) void softmax_k(
    const float* __restrict__ energy, const float* __restrict__ bval,
    float* __restrict__ Asm, float* __restrict__ u)
{
  const int row = blockIdx.x;             // b*256 + i
  const int l = threadIdx.x;              // 0..63
  const float* e = energy + (size_t)row * 256;
  float v0 = e[l], v1 = e[l + 64], v2 = e[l + 128], v3 = e[l + 192];
  float mx = fmaxf(fmaxf(v0, v1), fmaxf(v2, v3));
  #pragma unroll
  for (int o = 32; o > 0; o >>= 1) mx = fmaxf(mx, __shfl_xor(mx, o));
  v0 = __expf(v0 - mx); v1 = __expf(v1 - mx);
  v2 = __expf(v2 - mx); v3 = __expf(v3 - mx);
  float s = v0 + v1 + v2 + v3;
  #pragma unroll
  for (int o = 32; o > 0; o >>= 1) s += __shfl_xor(s, o);
  const float inv = 1.0f / s;
  v0 *= inv; v1 *= inv; v2 *= inv; v3 *= inv;
  float* Ao = Asm + (size_t)row * 256;
  Ao[l] = v0; Ao[l + 64] = v1; Ao[l + 128] = v2; Ao[l + 192] = v3;
  float ub = v0 * bval[l] + v1 * bval[l + 64] + v2 * bval[l + 128] + v3 * bval[l + 192];
  #pragma unroll
  for (int o = 32; o > 0; o >>= 1) ub += __shfl_xor(ub, o);
  if (l == 0) u[row] = ub;
}

// ---------------- kernel 2: batched fp32 GEMM C = A @ B, 64x64 tile, k-major LDS
__global__ __launch_bounds__(256) void gemm2_k(
    const float* __restrict__ A, int lda, int sA,
    const float* __restrict__ B, int ldb, int sB,
    float* __restrict__ C, int ldc, int sC, int K)
{
  const int bz = blockIdx.z;
  A += (size_t)bz * sA; B += (size_t)bz * sB; C += (size_t)bz * sC;
  const int m0 = blockIdx.y * 64, n0 = blockIdx.x * 64;
  __shared__ float AsT[16][68];   // [k][m], 272B rows (16B-aligned)
  __shared__ float Bs[16][68];    // [k][n]
  const int t = threadIdx.x, tx = t & 15, ty = t >> 4;
  const int ar = t >> 2, ak = (t & 3) * 4;     // A stage: row, k-quad
  const int br = t >> 4, bc = (t & 15) * 4;    // B stage: k-row, col-quad
  float acc[4][4] = {};
  for (int k0 = 0; k0 < K; k0 += 16) {
    float4 av = *(const float4*)(A + (size_t)(m0 + ar) * lda + k0 + ak);
    float4 bv = *(const float4*)(B + (size_t)(k0 + br) * ldb + n0 + bc);
    __syncthreads();
    AsT[ak][ar] = av.x; AsT[ak + 1][ar] = av.y;
    AsT[ak + 2][ar] = av.z; AsT[ak + 3][ar] = av.w;
    *(float4*)&Bs[br][bc] = bv;
    __syncthreads();
    #pragma unroll
    for (int kk = 0; kk < 16; ++kk) {
      float4 a4 = *(const float4*)&AsT[kk][ty * 4];
      float4 b4 = *(const float4*)&Bs[kk][tx * 4];
      const float aa[4] = {a4.x, a4.y, a4.z, a4.w};
      const float bb[4] = {b4.x, b4.y, b4.z, b4.w};
      #pragma unroll
      for (int i = 0; i < 4; ++i)
        #pragma unroll
        for (int j = 0; j < 4; ++j) acc[i][j] = fmaf(aa[i], bb[j], acc[i][j]);
    }
  }
  #pragma unroll
  for (int i = 0; i < 4; ++i) {
    float4 cv = {acc[i][0], acc[i][1], acc[i][2], acc[i][3]};
    *(float4*)(C + (size_t)(m0 + ty * 4 + i) * ldc + n0 + tx * 4) = cv;
  }
}

// ---------------- kernel 3: c[b][o] = gamma*(W_re[o,:]·u[b,:] + b_re[o])
__global__ __launch_bounds__(256) void bias_k(
    const float* __restrict__ wre, const float* __restrict__ u,
    const float* __restrict__ bre, const float* __restrict__ gp,
    float* __restrict__ c)
{
  const int idx = blockIdx.x * 256 + threadIdx.x;  // 0..4095
  const int b = idx >> 9, o = idx & 511;
  const float* wrow = wre + (size_t)o * 256;
  const float* uu = u + b * 256;
  float s = 0.f;
  for (int j = 0; j < 256; ++j) s += wrow[j] * uu[j];
  c[idx] = gp[0] * (s + bre[o]);
}

// ---------------- kernel 4: P (fp32 row-major) -> gamma-scaled bf16 fragment-linear
// Ps flat index = (((b*16 + kt)*32 + mt)*64 + lane)*8 + j
//   lane = kg*16 + (m&15), kg = (k>>3)&3, kt = k>>5, mt = m>>4, j = k&7
__global__ __launch_bounds__(256) void pswz_k(
    const float* __restrict__ P, const float* __restrict__ gp,
    ushort_t* __restrict__ Ps)
{
  const int d = blockIdx.x * 256 + threadIdx.x;    // 0..2097151
  const int j = d & 7, lane = (d >> 3) & 63, mt = (d >> 9) & 31;
  const int kt = (d >> 14) & 15, b = d >> 18;
  const int kg = lane >> 4, mr = lane & 15;
  const int m = mt * 16 + mr, k = kt * 32 + kg * 8 + j;
  Ps[d] = f2bf(gp[0] * P[((size_t)b * 512 + m) * 512 + k]);
}

// ---------------- kernel 5: out[b] = (gamma*P[b])@x[b] + 2*x[b] + c[b]
// 128x128 tile, BK=64, 4 waves (2x2), 8 K-iters. Key round-5 changes:
//  * lds_barrier() (lgkmcnt(0)+raw s_barrier) instead of __syncthreads —
//    __syncthreads' implicit vmcnt(0) was draining the x-prefetch queue
//    every iteration (both prior rounds ~2 TB/s effective).
//  * no sched_barrier(0) pins (m141 lesson), single af buffer, single stg
//    buffer -> target <=170 regs = 3 waves/SIMD (12 waves/CU).
__global__ __launch_bounds__(256, 3) void main_k(
    const ushort_t* __restrict__ Ps, const float* __restrict__ x,
    const float* __restrict__ cvec, float* __restrict__ out)
{
  __shared__ __align__(16) ushort_t Blds[2][8192];  // [buf][col*64 + k], XOR-swizzled

  const int bid = blockIdx.x;
  const int b = bid & 7;             // batch -> XCD pin (nwg%8==0, bijective)
  const int yb = (bid >> 3) & 3;
  const int n0 = (bid >> 5) * 128;
  const int m0 = yb * 128;

  const int t = threadIdx.x, lane = t & 63;
  const int w = t >> 6, wr = w >> 1, wc = w & 1;

  const float* xb = x + (size_t)b * (512 * 16384);
  const int c4 = t & 31;           // cols 4c4..4c4+3
  const int r0 = (t >> 5) * 8;     // k rows r0..r0+7 within the 64-row tile
  const int xcol = n0 + 4 * c4;
  const int mtb = yb * 8 + wr * 4;

  f32x4 acc[4][4];
  #pragma unroll
  for (int i = 0; i < 4; ++i)
    #pragma unroll
    for (int j = 0; j < 4; ++j) acc[i][j] = (f32x4){0.f, 0.f, 0.f, 0.f};

  float4 stg[8];     // single staging buffer: load(kt+2) issued right after
                     // writeTile(kt+1) consumed it -> ~1 iter of latency cover
  bf16x8 af[8];      // single A-fragment buffer (L2-resident Ps)

  auto loadTile = [&](int kt) {
    #pragma unroll
    for (int i = 0; i < 8; ++i)
      stg[i] = *(const float4*)(xb + (size_t)(kt * 64 + r0 + i) * 16384 + xcol);
  };
  auto loadA = [&](int kt) {
    #pragma unroll
    for (int kk = 0; kk < 2; ++kk)
      #pragma unroll
      for (int i = 0; i < 4; ++i)
        af[kk * 4 + i] = *(const bf16x8*)(
            Ps + ((size_t)((b * 16 + (kt * 2 + kk)) * 32 + (mtb + i))) * 512
               + (size_t)lane * 8);
  };
  auto writeTile = [&](int bufI) {
    char* base = (char*)&Blds[bufI][0];
    #pragma unroll
    for (int cc = 0; cc < 4; ++cc) {
      const int col = 4 * c4 + cc;
      u32x4 wv;
      #pragma unroll
      for (int p = 0; p < 4; ++p) {
        const float* f0 = (const float*)&stg[2 * p];
        const float* f1 = (const float*)&stg[2 * p + 1];
        wv[p] = cvt_pk_bf16(f0[cc], f1[cc]);   // lo=row 2p, hi=row 2p+1
      }
      const int swz = ((col >> 2) ^ col) & 7;
      const int off = col * 128 + ((r0 * 2) ^ (swz << 4));
      *(u32x4*)(base + off) = wv;
    }
  };

  // prologue: tile0 staged (one exposed-latency load), x(1) + A(0) in flight
  loadTile(0);
  loadA(0);
  writeTile(0);
  loadTile(1);
  lds_barrier();

  #pragma unroll
  for (int kt = 0; kt < 8; ++kt) {
    // stage tile kt+1 (stg holds x(kt+1)); compiler emits counted vmcnt
    if (kt < 7) writeTile((kt + 1) & 1);
    // re-issue stg <- x(kt+2): consumed at next iter's writeTile (~1 iter away)
    if (kt < 6) loadTile(kt + 2);

    // compute on tile kt: 8 ds_read_b128 + 32 MFMA, af(kt) already in regs
    const char* base = (const char*)&Blds[kt & 1][0];
    #pragma unroll
    for (int kk = 0; kk < 2; ++kk) {
      #pragma unroll
      for (int j = 0; j < 4; ++j) {
        const int col = wc * 64 + j * 16 + (lane & 15);
        const int kb = kk * 64 + (lane >> 4) * 16;
        const int swz = ((col >> 2) ^ col) & 7;
        const bf16x8 bf = *(const bf16x8*)(base + col * 128 + (kb ^ (swz << 4)));
        #pragma unroll
        for (int i = 0; i < 4; ++i)
          acc[i][j] = __builtin_amdgcn_mfma_f32_16x16x32_bf16(af[kk * 4 + i], bf, acc[i][j], 0, 0, 0);
      }
    }

    // refill af <- A(kt+1): WAR-safe (MFMAs read sources at issue; L2 load
    // returns much later), covered by the next barrier-to-MFMA distance
    if (kt < 7) loadA(kt + 1);

    lds_barrier();   // LDS visibility only; vmem prefetches stay in flight
  }

  // epilogue: out = acc + 2*x + c   (C/D layout: col=lane&15, row=(lane>>4)*4+r)
  float* ob = out + (size_t)b * (512 * 16384);
  const float* cb_base = cvec + b * 512 + m0;
  #pragma unroll
  for (int i = 0; i < 4; ++i) {
    #pragma unroll
    for (int r = 0; r < 4; ++r) {
      const int lm = wr * 64 + i * 16 + (lane >> 4) * 4 + r;
      const size_t gm = (size_t)(m0 + lm);
      const float cb = cb_base[lm];
      #pragma unroll
      for (int j = 0; j < 4; ++j) {
        const int gn = n0 + wc * 64 + j * 16 + (lane & 15);
        const size_t off = gm * 16384 + gn;
        ob[off] = fmaf(2.0f, xb[off], acc[i][j][r] + cb);
      }
    }
  }
}

extern "C" void kernel_launch(void* const* d_in, const int* in_sizes, int n_in,
                              void* d_out, int out_size, void* d_ws, size_t ws_size,
                              hipStream_t stream) {
  const float* energy  = (const float*)d_in[0];  // [8,256,256]
  const float* x       = (const float*)d_in[1];  // [8,512,128,128]
  const float* w_value = (const float*)d_in[2];  // [256,512]
  const float* b_value = (const float*)d_in[3];  // [256]
  const float* w_re    = (const float*)d_in[4];  // [512,256]
  const float* b_re    = (const float*)d_in[5];  // [512]
  const float* gamma   = (const float*)d_in[6];  // [1]
  float* out = (float*)d_out;

  char* ws = (char*)d_ws;
  float*    Asm = (float*)(ws);                  // 8*256*256 f32   (2 MB)
  float*    u   = (float*)(ws + 2097152);        // 8*256 f32       (8 KB)
  float*    T   = (float*)(ws + 2105344);        // 8*512*256 f32   (4 MB)
  float*    P   = (float*)(ws + 6299648);        // 8*512*512 f32   (8 MB)
  float*    c   = (float*)(ws + 14688256);       // 8*512 f32       (16 KB)
  ushort_t* Ps  = (ushort_t*)(ws + 14704640);    // 8*512*512 bf16  (4 MB)

  softmax_k<<<2048, 64, 0, stream>>>(energy, b_value, Asm, u);
  gemm2_k<<<dim3(4, 8, 8), 256, 0, stream>>>(w_re, 256, 0,
                                             Asm, 256, 256 * 256,
                                             T, 256, 512 * 256, 256);
  gemm2_k<<<dim3(8, 8, 8), 256, 0, stream>>>(T, 256, 512 * 256,
                                             w_value, 512, 0,
                                             P, 512, 512 * 512, 256);
  bias_k<<<16, 256, 0, stream>>>(w_re, u, b_re, gamma, c);
  pswz_k<<<8192, 256, 0, stream>>>(P, gamma, Ps);
  main_k<<<4096, 256, 0, stream>>>(Ps, x, c, out);
}